// Round 8
// baseline (74.870 us; speedup 1.0000x reference)
//
#include <hip/hip_runtime.h>

#define NPTS  131072        // B*G
#define NCELL 262144        // 4 * 256 * 256
#define ZR    NPTS          // zero-row slot in fbs

typedef __attribute__((ext_vector_type(8)))  _Float16 half8v;
typedef __attribute__((ext_vector_type(16))) float    f32x16;

// ---- sigmoid emulating the reference f32 pipeline (bit-faithful) ----------
__device__ __forceinline__ float sigf(float x) {
    x = fminf(fmaxf(x, -9.21f), 9.21f);
    float t = (float)exp(-(double)x);
    return 1.0f / (1.0f + t);
}

// ---- fused front-end -------------------------------------------------------
// blocks [0,512):  sigmoid + per-block min + clear {grd, hist, wrank}
// blocks [512,530): W -> 32x32x16 f16 B-fragments (+ fbs zero row)
__global__ __launch_bounds__(256) void k_front(const float* __restrict__ anchor,
                                               const float* __restrict__ W,
                                               float* __restrict__ s0a,
                                               float* __restrict__ s1a,
                                               float2* __restrict__ blockmin,
                                               _Float16* __restrict__ bpk,
                                               _Float16* __restrict__ fbs,
                                               int* __restrict__ grd,
                                               int* __restrict__ hist,
                                               int* __restrict__ wrank) {
    const int bid = blockIdx.x;
    if (bid < 512) {
        __shared__ float red[8];
        int i = bid * 256 + threadIdx.x;            // [0,131072)
        int2 mone = {-1, -1};
        int2 zero = {0, 0};
        int2 zrr  = {ZR, ZR};
        ((int2*)grd)[i]   = mone;                   // rulebook grid = -1
        ((int2*)hist)[i]  = zero;                   // cell histogram = 0
        ((int2*)wrank)[i] = zrr;                    // winner rank = zero row
        float2 a = ((const float2*)anchor)[i];
        float s0 = sigf(a.x);
        float s1 = sigf(a.y);
        s0a[i] = s0;
        s1a[i] = s1;
        float m0 = s0, m1 = s1;
        #pragma unroll
        for (int off = 32; off; off >>= 1) {
            m0 = fminf(m0, __shfl_down(m0, off));
            m1 = fminf(m1, __shfl_down(m1, off));
        }
        int wv = threadIdx.x >> 6;
        if ((threadIdx.x & 63) == 0) { red[wv * 2] = m0; red[wv * 2 + 1] = m1; }
        __syncthreads();
        if (threadIdx.x == 0) {
            float a0 = fminf(fminf(red[0], red[2]), fminf(red[4], red[6]));
            float a1 = fminf(fminf(red[1], red[3]), fminf(red[5], red[7]));
            blockmin[bid] = make_float2(a0, a1);
        }
    } else {
        if (bid == 512 && threadIdx.x < 8) {        // fbs zero row (slot ZR)
            half8v z = {};
            *(half8v*)(fbs + ((long)ZR << 6) + threadIdx.x * 8) = z;
        }
        // frag q = t*8 + ks*2 + nt; lane l: B[k=ks*16+(l>>5)*8+j][n=nt*32+(l&31)]
        int tid = (bid - 512) * 256 + threadIdx.x;
        if (tid >= 4608) return;
        int l  = tid & 63;
        int q  = tid >> 6;
        int nt = q & 1;
        int ks = (q >> 1) & 3;
        int t  = q >> 3;
        int n  = nt * 32 + (l & 31);
        int kb = ks * 16 + (l >> 5) * 8;
        half8v v;
        #pragma unroll
        for (int j = 0; j < 8; ++j)
            v[j] = (_Float16)W[(t * 64 + kb + j) * 64 + n];
        ((half8v*)bpk)[q * 64 + l] = v;
    }
}

// ---- cell key + rulebook scatter (max id wins) + histogram ----------------
__global__ __launch_bounds__(256) void k_grid(const float* __restrict__ s0a,
                                              const float* __restrict__ s1a,
                                              const float2* __restrict__ blockmin,
                                              int* __restrict__ pidx,
                                              int* __restrict__ grid,
                                              int* __restrict__ hist) {
    __shared__ float red[8];
    float2 ba = blockmin[threadIdx.x];
    float2 bb = blockmin[threadIdx.x + 256];
    float m0 = fminf(ba.x, bb.x), m1 = fminf(ba.y, bb.y);
    #pragma unroll
    for (int off = 32; off; off >>= 1) {
        m0 = fminf(m0, __shfl_down(m0, off));
        m1 = fminf(m1, __shfl_down(m1, off));
    }
    int wv = threadIdx.x >> 6;
    if ((threadIdx.x & 63) == 0) { red[wv * 2] = m0; red[wv * 2 + 1] = m1; }
    __syncthreads();
    m0 = fminf(fminf(red[0], red[2]), fminf(red[4], red[6]));
    m1 = fminf(fminf(red[1], red[3]), fminf(red[5], red[7]));

    int i = blockIdx.x * 256 + threadIdx.x;
    int iy = (int)((s0a[i] - m0) * 256.0f);
    int ix = (int)((s1a[i] - m1) * 256.0f);
    int ck = ((i >> 15) << 16) | (iy << 8) | ix;    // full cell key [0, NCELL)
    pidx[i] = ck;
    atomicMax(&grid[ck], i);
    atomicAdd(&hist[ck], 1);
}

// ---- counting-sort scan: phase 1 (per-block of 1024 cells) ----------------
__global__ __launch_bounds__(256) void k_scan1(const int* __restrict__ hist,
                                               int* __restrict__ starts,
                                               int* __restrict__ bsum) {
    __shared__ int sd[256];
    int tid = threadIdx.x;
    int4 h = ((const int4*)hist)[blockIdx.x * 256 + tid];
    int s = h.x + h.y + h.z + h.w;
    sd[tid] = s;
    __syncthreads();
    #pragma unroll
    for (int off = 1; off < 256; off <<= 1) {
        int v = (tid >= off) ? sd[tid - off] : 0;
        __syncthreads();
        sd[tid] += v;
        __syncthreads();
    }
    int excl = sd[tid] - s;                         // block-local exclusive start
    int4 o;
    o.x = excl; o.y = o.x + h.x; o.z = o.y + h.y; o.w = o.z + h.z;
    ((int4*)starts)[blockIdx.x * 256 + tid] = o;
    if (tid == 255) bsum[blockIdx.x] = sd[255];
}

// ---- phase 2: exclusive scan of the 256 block sums ------------------------
__global__ __launch_bounds__(256) void k_scan2(const int* __restrict__ bsum,
                                               int* __restrict__ boff) {
    __shared__ int sd[256];
    int tid = threadIdx.x;
    int s = bsum[tid];
    sd[tid] = s;
    __syncthreads();
    #pragma unroll
    for (int off = 1; off < 256; off <<= 1) {
        int v = (tid >= off) ? sd[tid - off] : 0;
        __syncthreads();
        sd[tid] += v;
        __syncthreads();
    }
    boff[tid] = sd[tid] - s;
}

// ---- scatter: place points into cell-sorted order + convert features ------
// slot = boff[ck>>10] + blockLocalStart[ck] + rank  (rank via atomicAdd)
__global__ __launch_bounds__(256) void k_scat(const float* __restrict__ feats,
                                              const int* __restrict__ pidx,
                                              const int* __restrict__ grd,
                                              const int* __restrict__ boff,
                                              int* __restrict__ starts,
                                              int* __restrict__ sorted,
                                              int* __restrict__ skey,
                                              int* __restrict__ wrank,
                                              _Float16* __restrict__ fbs) {
    int i = blockIdx.x * 256 + threadIdx.x;
    int ck = pidx[i];
    int slot = boff[ck >> 10] + atomicAdd(&starts[ck], 1);
    sorted[slot] = i;
    skey[slot]   = ck;
    if (grd[ck] == i) wrank[ck] = slot;             // winner's sorted rank
    const float4* src = (const float4*)(feats + ((long)i << 6));
    half8v* dst = (half8v*)(fbs + ((long)slot << 6));
    #pragma unroll
    for (int q = 0; q < 8; ++q) {
        float4 f = src[2 * q];
        float4 g = src[2 * q + 1];
        half8v o = {(_Float16)f.x, (_Float16)f.y, (_Float16)f.z, (_Float16)f.w,
                    (_Float16)g.x, (_Float16)g.y, (_Float16)g.z, (_Float16)g.w};
        dst[q] = o;
    }
}

// ---- MFMA conv over SORTED points: wave = 32 points x 64 couts ------------
// Gathers: wrank[cell] (cell-local) -> fbs[rank] (rank-local). Same-cell lanes
// broadcast. A-frag: lane l holds A[row=l&31][k=ks*16+(l>>5)*8+j].
// C/D: col=lane&31, row=(reg&3)+8*(reg>>2)+4*(lane>>5)   [HW-verified]
__global__ __launch_bounds__(256, 4) void k_mconv(const _Float16* __restrict__ fbs,
                                                  const _Float16* __restrict__ bpk,
                                                  const int* __restrict__ skey,
                                                  const int* __restrict__ sorted,
                                                  const int* __restrict__ wrank,
                                                  float* __restrict__ out) {
    const int lane  = threadIdx.x & 63;
    const int wv    = threadIdx.x >> 6;
    const int pbase = (blockIdx.x << 7) + (wv << 5);
    const int prow  = lane & 31;
    const int khalf = lane >> 5;

    const int ck = skey[pbase + prow];
    const int iy = (ck >> 8) & 255;
    const int ix = ck & 255;
    const int cb = ck & 0x30000;

    int row[9];
    #pragma unroll
    for (int t = 0; t < 9; ++t) {
        const int ny = iy + t / 3 - 1;
        const int nx = ix + t % 3 - 1;
        row[t] = ((unsigned)ny < 256u && (unsigned)nx < 256u)
                   ? wrank[cb + (ny << 8) + nx] : ZR;
    }

    const half8v* bq = (const half8v*)bpk + lane;

    f32x16 acc0, acc1;
    #pragma unroll
    for (int r = 0; r < 16; ++r) { acc0[r] = 0.0f; acc1[r] = 0.0f; }

    #pragma unroll
    for (int t = 0; t < 9; ++t) {
        const half8v* arow = (const half8v*)(fbs + ((long)row[t] << 6));
        half8v a0 = arow[khalf];
        half8v a1 = arow[2 + khalf];
        half8v a2 = arow[4 + khalf];
        half8v a3 = arow[6 + khalf];
        const half8v* bt = bq + (t << 9);          // 8 frags * 64 lanes per tap
        acc0 = __builtin_amdgcn_mfma_f32_32x32x16_f16(a0, bt[0 * 64], acc0, 0, 0, 0);
        acc1 = __builtin_amdgcn_mfma_f32_32x32x16_f16(a0, bt[1 * 64], acc1, 0, 0, 0);
        acc0 = __builtin_amdgcn_mfma_f32_32x32x16_f16(a1, bt[2 * 64], acc0, 0, 0, 0);
        acc1 = __builtin_amdgcn_mfma_f32_32x32x16_f16(a1, bt[3 * 64], acc1, 0, 0, 0);
        acc0 = __builtin_amdgcn_mfma_f32_32x32x16_f16(a2, bt[4 * 64], acc0, 0, 0, 0);
        acc1 = __builtin_amdgcn_mfma_f32_32x32x16_f16(a2, bt[5 * 64], acc1, 0, 0, 0);
        acc0 = __builtin_amdgcn_mfma_f32_32x32x16_f16(a3, bt[6 * 64], acc0, 0, 0, 0);
        acc1 = __builtin_amdgcn_mfma_f32_32x32x16_f16(a3, bt[7 * 64], acc1, 0, 0, 0);
    }

    #pragma unroll
    for (int r = 0; r < 16; ++r) {
        int spos = pbase + (r & 3) + ((r >> 2) << 3) + (khalf << 2);
        int op   = sorted[spos];                    // original point id
        out[(long)op * 64 + prow]      = acc0[r];
        out[(long)op * 64 + 32 + prow] = acc1[r];
    }
}

extern "C" void kernel_launch(void* const* d_in, const int* in_sizes, int n_in,
                              void* d_out, int out_size, void* d_ws, size_t ws_size,
                              hipStream_t stream) {
    const float* inst   = (const float*)d_in[0]; // (B,G,64)
    const float* anchor = (const float*)d_in[1]; // (B,G,2)
    const float* W      = (const float*)d_in[2]; // (3,3,64,64)
    float* out = (float*)d_out;

    char* ws = (char*)d_ws;
    float*     s0a    = (float*)(ws);                    // 512 KB
    float*     s1a    = (float*)(ws + 524288);           // 512 KB
    int*       pidx   = (int*)(ws + 1048576);            // 512 KB (cell keys)
    int*       grd    = (int*)(ws + 1572864);            // 1 MB
    int*       hist   = (int*)(ws + 2621440);            // 1 MB
    int*       starts = (int*)(ws + 3670016);            // 1 MB
    int*       wrank  = (int*)(ws + 4718592);            // 1 MB
    float2*    bmin   = (float2*)(ws + 5767168);         // 4 KB
    int*       bsum   = (int*)(ws + 5771264);            // 1 KB
    int*       boff   = (int*)(ws + 5772288);            // 1 KB
    int*       sorted = (int*)(ws + 5773312);            // 512 KB
    int*       skey   = (int*)(ws + 6297600);            // 512 KB
    _Float16*  bpk    = (_Float16*)(ws + 6821888);       // 72 KB
    _Float16*  fbs    = (_Float16*)(ws + 6897664);       // (NPTS+1)*128 B = 16.8 MB

    k_front<<<530,  256, 0, stream>>>(anchor, W, s0a, s1a, bmin, bpk, fbs, grd, hist, wrank);
    k_grid <<<512,  256, 0, stream>>>(s0a, s1a, bmin, pidx, grd, hist);
    k_scan1<<<256,  256, 0, stream>>>(hist, starts, bsum);
    k_scan2<<<1,    256, 0, stream>>>(bsum, boff);
    k_scat <<<512,  256, 0, stream>>>(inst, pidx, grd, boff, starts, sorted, skey, wrank, fbs);
    k_mconv<<<1024, 256, 0, stream>>>(fbs, bpk, skey, sorted, wrank, out);
}

// Round 9
// 53.020 us; speedup vs baseline: 1.4121x; 1.4121x over previous
//
#include <hip/hip_runtime.h>

#define NPTS  131072        // B*G
#define GPTS  32768         // G

typedef __attribute__((ext_vector_type(4)))  _Float16 half4v;
typedef __attribute__((ext_vector_type(8)))  _Float16 half8v;
typedef __attribute__((ext_vector_type(16))) float    f32x16;

// ---- sigmoid emulating the reference f32 pipeline (bit-faithful) ----------
__device__ __forceinline__ float sigf(float x) {
    x = fminf(fmaxf(x, -9.21f), 9.21f);
    float t = (float)exp(-(double)x);
    return 1.0f / (1.0f + t);
}

// ---- fused front-end -------------------------------------------------------
// blocks [0,512):    sigmoid + per-block min + grid clear
// blocks [512,530):  W -> 32x32x16 f16 B-fragments
// blocks [530,2578): feats f32 -> f16 rows (+1 zero row)
__global__ __launch_bounds__(256) void k_front(const float* __restrict__ anchor,
                                               const float* __restrict__ W,
                                               const float* __restrict__ feats,
                                               float* __restrict__ s0a,
                                               float* __restrict__ s1a,
                                               float2* __restrict__ blockmin,
                                               _Float16* __restrict__ bpk,
                                               _Float16* __restrict__ fb,
                                               int* __restrict__ grd) {
    const int bid = blockIdx.x;
    if (bid < 512) {
        __shared__ float red[8];
        int i = bid * 256 + threadIdx.x;            // [0,131072)
        int2 mone = {-1, -1};
        ((int2*)grd)[i] = mone;                     // clear 1 MB rulebook grid
        float2 a = ((const float2*)anchor)[i];
        float s0 = sigf(a.x);
        float s1 = sigf(a.y);
        s0a[i] = s0;
        s1a[i] = s1;
        float m0 = s0, m1 = s1;
        #pragma unroll
        for (int off = 32; off; off >>= 1) {
            m0 = fminf(m0, __shfl_down(m0, off));
            m1 = fminf(m1, __shfl_down(m1, off));
        }
        int wv = threadIdx.x >> 6;
        if ((threadIdx.x & 63) == 0) { red[wv * 2] = m0; red[wv * 2 + 1] = m1; }
        __syncthreads();
        if (threadIdx.x == 0) {
            float a0 = fminf(fminf(red[0], red[2]), fminf(red[4], red[6]));
            float a1 = fminf(fminf(red[1], red[3]), fminf(red[5], red[7]));
            blockmin[bid] = make_float2(a0, a1);
        }
    } else if (bid < 530) {
        // frag q = t*8 + ks*2 + nt; lane l: B[k=ks*16+(l>>5)*8+j][n=nt*32+(l&31)]
        int tid = (bid - 512) * 256 + threadIdx.x;
        if (tid >= 4608) return;
        int l  = tid & 63;
        int q  = tid >> 6;
        int nt = q & 1;
        int ks = (q >> 1) & 3;
        int t  = q >> 3;
        int n  = nt * 32 + (l & 31);
        int kb = ks * 16 + (l >> 5) * 8;
        half8v v;
        #pragma unroll
        for (int j = 0; j < 8; ++j)
            v[j] = (_Float16)W[(t * 64 + kb + j) * 64 + n];
        ((half8v*)bpk)[q * 64 + l] = v;
    } else {
        int tid = (bid - 530) * 256 + threadIdx.x;  // [0,524288)
        if (bid == 530 && threadIdx.x < 8) {        // zero row NPTS
            half8v z = {};
            *(half8v*)(fb + (long)NPTS * 64 + threadIdx.x * 8) = z;
        }
        #pragma unroll
        for (int r = 0; r < 4; ++r) {
            long i = tid + (long)r * 524288;        // 2,097,152 float4 total
            float4 f = ((const float4*)feats)[i];
            half4v o = {(_Float16)f.x, (_Float16)f.y, (_Float16)f.z, (_Float16)f.w};
            *(half4v*)(fb + i * 4) = o;
        }
    }
}

// ---- cell index + rulebook scatter (max id wins); min-fold at head --------
__global__ __launch_bounds__(256) void k_grid(const float* __restrict__ s0a,
                                              const float* __restrict__ s1a,
                                              const float2* __restrict__ blockmin,
                                              int* __restrict__ pidx,
                                              int* __restrict__ grid) {
    __shared__ float red[8];
    float2 ba = blockmin[threadIdx.x];
    float2 bb = blockmin[threadIdx.x + 256];
    float m0 = fminf(ba.x, bb.x), m1 = fminf(ba.y, bb.y);
    #pragma unroll
    for (int off = 32; off; off >>= 1) {
        m0 = fminf(m0, __shfl_down(m0, off));
        m1 = fminf(m1, __shfl_down(m1, off));
    }
    int wv = threadIdx.x >> 6;
    if ((threadIdx.x & 63) == 0) { red[wv * 2] = m0; red[wv * 2 + 1] = m1; }
    __syncthreads();
    m0 = fminf(fminf(red[0], red[2]), fminf(red[4], red[6]));
    m1 = fminf(fminf(red[1], red[3]), fminf(red[5], red[7]));

    int i = blockIdx.x * 256 + threadIdx.x;
    int iy = (int)((s0a[i] - m0) * 256.0f);
    int ix = (int)((s1a[i] - m1) * 256.0f);
    pidx[i] = (iy << 8) | ix;
    int b = i >> 15;
    atomicMax(&grid[(b << 16) + (iy << 8) + ix], i);
}

// ---- MFMA conv: wave = 32 points x 64 couts; B-frags LDS-staged ------------
// Taps 0..5 (48 KB) staged in LDS once per block; taps 6..8 (24 KB) read from
// global (block-shared, L1/L2). A-frag: lane l holds A[row=l&31][k=ks*16+(l>>5)*8+j].
// C/D: col=lane&31, row=(reg&3)+8*(reg>>2)+4*(lane>>5)   [HW-verified]
__global__ __launch_bounds__(256, 3) void k_mconv(const _Float16* __restrict__ fb,
                                                  const _Float16* __restrict__ bpk,
                                                  const int* __restrict__ pidx,
                                                  const int* __restrict__ grid,
                                                  float* __restrict__ out) {
    __shared__ half8v bsh[3072];                    // 6 taps * 8 frags * 64 lanes = 48 KB
    {
        const half8v* bg = (const half8v*)bpk;
        #pragma unroll
        for (int q = 0; q < 12; ++q)
            bsh[threadIdx.x + q * 256] = bg[threadIdx.x + q * 256];
    }

    const int lane  = threadIdx.x & 63;
    const int wv    = threadIdx.x >> 6;
    const int pbase = (blockIdx.x << 7) + (wv << 5);
    const int prow  = lane & 31;
    const int khalf = lane >> 5;
    const int p     = pbase + prow;

    const int pk = pidx[p];
    const int iy = pk >> 8;
    const int ix = pk & 255;
    const int* gb = grid + ((p >> 15) << 16);

    int nid[9];
    #pragma unroll
    for (int t = 0; t < 9; ++t) {
        const int ny = iy + t / 3 - 1;
        const int nx = ix + t % 3 - 1;
        int n = ((unsigned)ny < 256u && (unsigned)nx < 256u) ? gb[(ny << 8) + nx] : -1;
        nid[t] = (n < 0) ? NPTS : n;               // zero row for invalid taps
    }

    __syncthreads();                                // LDS B-frags ready

    f32x16 acc0, acc1;
    #pragma unroll
    for (int r = 0; r < 16; ++r) { acc0[r] = 0.0f; acc1[r] = 0.0f; }

    // taps 0..5: B from LDS
    #pragma unroll
    for (int t = 0; t < 6; ++t) {
        const half8v* arow = (const half8v*)(fb + ((long)nid[t] << 6));
        half8v a0 = arow[khalf];
        half8v a1 = arow[2 + khalf];
        half8v a2 = arow[4 + khalf];
        half8v a3 = arow[6 + khalf];
        const half8v* bt = &bsh[(t << 9) + lane];
        acc0 = __builtin_amdgcn_mfma_f32_32x32x16_f16(a0, bt[0 * 64], acc0, 0, 0, 0);
        acc1 = __builtin_amdgcn_mfma_f32_32x32x16_f16(a0, bt[1 * 64], acc1, 0, 0, 0);
        acc0 = __builtin_amdgcn_mfma_f32_32x32x16_f16(a1, bt[2 * 64], acc0, 0, 0, 0);
        acc1 = __builtin_amdgcn_mfma_f32_32x32x16_f16(a1, bt[3 * 64], acc1, 0, 0, 0);
        acc0 = __builtin_amdgcn_mfma_f32_32x32x16_f16(a2, bt[4 * 64], acc0, 0, 0, 0);
        acc1 = __builtin_amdgcn_mfma_f32_32x32x16_f16(a2, bt[5 * 64], acc1, 0, 0, 0);
        acc0 = __builtin_amdgcn_mfma_f32_32x32x16_f16(a3, bt[6 * 64], acc0, 0, 0, 0);
        acc1 = __builtin_amdgcn_mfma_f32_32x32x16_f16(a3, bt[7 * 64], acc1, 0, 0, 0);
    }
    // taps 6..8: B from global (24 KB shared by all waves)
    #pragma unroll
    for (int t = 6; t < 9; ++t) {
        const half8v* arow = (const half8v*)(fb + ((long)nid[t] << 6));
        half8v a0 = arow[khalf];
        half8v a1 = arow[2 + khalf];
        half8v a2 = arow[4 + khalf];
        half8v a3 = arow[6 + khalf];
        const half8v* bt = (const half8v*)bpk + (t << 9) + lane;
        acc0 = __builtin_amdgcn_mfma_f32_32x32x16_f16(a0, bt[0 * 64], acc0, 0, 0, 0);
        acc1 = __builtin_amdgcn_mfma_f32_32x32x16_f16(a0, bt[1 * 64], acc1, 0, 0, 0);
        acc0 = __builtin_amdgcn_mfma_f32_32x32x16_f16(a1, bt[2 * 64], acc0, 0, 0, 0);
        acc1 = __builtin_amdgcn_mfma_f32_32x32x16_f16(a1, bt[3 * 64], acc1, 0, 0, 0);
        acc0 = __builtin_amdgcn_mfma_f32_32x32x16_f16(a2, bt[4 * 64], acc0, 0, 0, 0);
        acc1 = __builtin_amdgcn_mfma_f32_32x32x16_f16(a2, bt[5 * 64], acc1, 0, 0, 0);
        acc0 = __builtin_amdgcn_mfma_f32_32x32x16_f16(a3, bt[6 * 64], acc0, 0, 0, 0);
        acc1 = __builtin_amdgcn_mfma_f32_32x32x16_f16(a3, bt[7 * 64], acc1, 0, 0, 0);
    }

    #pragma unroll
    for (int r = 0; r < 16; ++r) {
        int orow = pbase + (r & 3) + ((r >> 2) << 3) + (khalf << 2);
        out[(long)orow * 64 + prow]      = acc0[r];
        out[(long)orow * 64 + 32 + prow] = acc1[r];
    }
}

extern "C" void kernel_launch(void* const* d_in, const int* in_sizes, int n_in,
                              void* d_out, int out_size, void* d_ws, size_t ws_size,
                              hipStream_t stream) {
    const float* inst   = (const float*)d_in[0]; // (B,G,64)
    const float* anchor = (const float*)d_in[1]; // (B,G,2)
    const float* W      = (const float*)d_in[2]; // (3,3,64,64)
    float* out = (float*)d_out;

    char* ws = (char*)d_ws;
    float*     s0a  = (float*)(ws);                      // 512 KB
    float*     s1a  = (float*)(ws + 524288);             // 512 KB
    int*       pidx = (int*)(ws + 1048576);              // 512 KB
    int*       grd  = (int*)(ws + 1572864);              // 1 MB
    float2*    bmin = (float2*)(ws + 2621440);           // 4 KB (512 float2)
    _Float16*  fb   = (_Float16*)(ws + 2625536);         // (N+1)*64 f16
    _Float16*  bpk  = (_Float16*)(ws + 19402880);        // 72 KB

    k_front<<<2578, 256, 0, stream>>>(anchor, W, inst, s0a, s1a, bmin, bpk, fb, grd);
    k_grid <<<512,  256, 0, stream>>>(s0a, s1a, bmin, pidx, grd);
    k_mconv<<<1024, 256, 0, stream>>>(fb, bpk, pidx, grd, out);
}